// Round 6
// baseline (303.968 us; speedup 1.0000x reference)
//
#include <hip/hip_runtime.h>
#include <math.h>

#define T_NTIME  2048
#define T_NBATCH 128
#define T_INSIZE 512
#define T_SIZE   16
#define T_NROWS  (T_NTIME * T_NBATCH)
#define MAT_STRIDE 24   // padded per-(chunk,b) transfer-matrix stride (floats)

__device__ __forceinline__ float sp_f(float v) {
  return fmaxf(v, 0.0f) + log1pf(__expf(-fabsf(v)));
}
__device__ __forceinline__ float tanh5_f(float v) {
  float a = fabsf(v);
  float e = __expf(-2.0f * a);
  float t = (1.0f - e) / (1.0f + e);
  return copysignf(5.0f * t, v);
}
__device__ __forceinline__ float lae_f(float a, float c) {
  float m = fmaxf(a, c);
  return m + log1pf(__expf(-fabsf(a - c)));
}

// ---------- K1: y = x @ W^T + b, activations; trans written pre-logZ ----------
// W operands are wave-uniform -> read W straight from global with uniform
// addresses so the compiler scalarizes them (s_load + constant cache) and the
// FMA becomes v_fmac v, s, v. No LDS at all (R5 limiter was the per-CU LDS
// pipe: 16K ds_read_b128/CU ~= 82us). x streamed per-lane in 128B groups with
// ping-pong register prefetch (validated: no HBM amplification, no spill).
__global__ __launch_bounds__(256, 4)
void k_gemm_act(const float* __restrict__ x, const float* __restrict__ W,
                const float* __restrict__ bias, float* __restrict__ out) {
  const int tid = threadIdx.x;
  const long row = (long)blockIdx.x * 256 + tid;
  const float* __restrict__ xp = x + row * T_INSIZE;

  float acc[T_SIZE];
#pragma unroll
  for (int s = 0; s < T_SIZE; ++s) acc[s] = 0.0f;

  float4 cur[4], nxt[4];
#pragma unroll
  for (int j = 0; j < 4; ++j) cur[j] = *(const float4*)(xp + j * 4);

  // Process k in 32 groups of 16 floats (64B per lane-group; two groups = one
  // 128B-aligned prefetch granule pair).
#define COMPUTE_GROUP(buf, gg)                                                  \
  do {                                                                          \
    _Pragma("unroll")                                                           \
    for (int j = 0; j < 4; ++j) {                                               \
      const float4 xv = buf[j];                                                 \
      _Pragma("unroll")                                                         \
      for (int s = 0; s < T_SIZE; ++s) {                                        \
        const float4 w4 = *(const float4*)(W + s * T_INSIZE + (gg) * 16 + j * 4); \
        acc[s] = fmaf(xv.x, w4.x, acc[s]);                                      \
        acc[s] = fmaf(xv.y, w4.y, acc[s]);                                      \
        acc[s] = fmaf(xv.z, w4.z, acc[s]);                                      \
        acc[s] = fmaf(xv.w, w4.w, acc[s]);                                      \
      }                                                                         \
    }                                                                           \
  } while (0)

#pragma unroll 1
  for (int g = 0; g < 32; g += 2) {
#pragma unroll
    for (int j = 0; j < 4; ++j) nxt[j] = *(const float4*)(xp + (g + 1) * 16 + j * 4);
    COMPUTE_GROUP(cur, g);
    if (g + 2 < 32) {
#pragma unroll
      for (int j = 0; j < 4; ++j) cur[j] = *(const float4*)(xp + (g + 2) * 16 + j * 4);
    }
    COMPUTE_GROUP(nxt, g + 1);
  }
#undef COMPUTE_GROUP

  float* op = out + row * T_SIZE;
  float4 v;
  v.x = 1.0f + sp_f(acc[0] + bias[0]);
  v.y = 1.0f + sp_f(acc[1] + bias[1]);
  v.z = 1.0f + sp_f(acc[2] + bias[2]);
  v.w = 1.0f + sp_f(acc[3] + bias[3]);
  *(float4*)(op + 0) = v;
  v.x = 0.1f + sp_f(acc[4] + bias[4]);
  v.y = 0.1f + sp_f(acc[5] + bias[5]);
  v.z = 0.1f + sp_f(acc[6] + bias[6]);
  v.w = 0.1f + sp_f(acc[7] + bias[7]);
  *(float4*)(op + 4) = v;
  v.x = tanh5_f(acc[8] + bias[8]);
  v.y = tanh5_f(acc[9] + bias[9]);
  v.z = tanh5_f(acc[10] + bias[10]);
  v.w = tanh5_f(acc[11] + bias[11]);
  *(float4*)(op + 8) = v;
  v.x = tanh5_f(acc[12] + bias[12]);
  v.y = tanh5_f(acc[13] + bias[13]);
  v.z = tanh5_f(acc[14] + bias[14]);
  v.w = tanh5_f(acc[15] + bias[15]);
  *(float4*)(op + 12) = v;
}

// ---------- K2a: per-(b, chunk, basis-col) chunk transfer-matrix columns ----------
__global__ void k_scan_chunks(const float* __restrict__ out, float* __restrict__ mats,
                              int nchunks) {
  const int gtid = blockIdx.x * blockDim.x + threadIdx.x;
  const int colslot = gtid & 7;
  const int b = (gtid >> 3) & (T_NBATCH - 1);
  const int chunk = gtid >> 10;
  if (chunk >= nchunks) return;
  if (colslot >= 5) return;

  const int steps = T_NTIME / nchunks;
  const int t0 = chunk * steps;
  const float NEG = -1e30f;
  float f0 = (colslot == 0) ? 0.0f : NEG;
  float f1 = (colslot == 1) ? 0.0f : NEG;
  float f2 = (colslot == 2) ? 0.0f : NEG;
  float f3 = (colslot == 3) ? 0.0f : NEG;
  const float t4 = (colslot == 4) ? 0.0f : NEG;

  const long stride = T_NBATCH * T_SIZE;
  const float* p = out + ((long)t0 * T_NBATCH + b) * T_SIZE + 8;
  float4 mv = *(const float4*)(p);
  float4 st = *(const float4*)(p + 4);
  for (int s = 0; s < steps; ++s) {
    const float* pn = (s + 1 < steps) ? p + stride : p;
    const float4 mvn = *(const float4*)(pn);
    const float4 stn = *(const float4*)(pn + 4);

    float m, ss0, ss1, ss2, ss3;
    m = fmaxf(fmaxf(f1, f2), fmaxf(f3, t4));
    ss0 = m + __logf(__expf(f1 - m) + __expf(f2 - m) + __expf(f3 - m) + __expf(t4 - m));
    m = fmaxf(fmaxf(f0, f2), fmaxf(f3, t4));
    ss1 = m + __logf(__expf(f0 - m) + __expf(f2 - m) + __expf(f3 - m) + __expf(t4 - m));
    m = fmaxf(fmaxf(f0, f1), fmaxf(f3, t4));
    ss2 = m + __logf(__expf(f0 - m) + __expf(f1 - m) + __expf(f3 - m) + __expf(t4 - m));
    m = fmaxf(fmaxf(f0, f1), fmaxf(f2, t4));
    ss3 = m + __logf(__expf(f0 - m) + __expf(f1 - m) + __expf(f2 - m) + __expf(t4 - m));

    const float n0 = lae_f(f0 + st.x, ss0 + mv.x);
    const float n1 = lae_f(f1 + st.y, ss1 + mv.y);
    const float n2 = lae_f(f2 + st.z, ss2 + mv.z);
    const float n3 = lae_f(f3 + st.w, ss3 + mv.w);
    f0 = n0; f1 = n1; f2 = n2; f3 = n3;
    mv = mvn; st = stn; p = pn;
  }
  float* d = mats + ((long)chunk * T_NBATCH + b) * MAT_STRIDE + colslot * 4;
  float4 o; o.x = f0; o.y = f1; o.z = f2; o.w = f3;
  *(float4*)d = o;
}

// ---------- K2b: serial combine of chunk matrices per batch; logZ/T out ----------
__global__ void k_combine(const float* __restrict__ mats, float* __restrict__ logz,
                          int nchunks) {
  const int tid = threadIdx.x;       // 0..511
  const int i = tid & 3;             // state row
  const int b = tid >> 2;            // batch
  if (b >= T_NBATCH) return;
  float v = 0.0f;                    // v[i]; implicit v[4] = 0 constant

  const float* Tb = mats + (long)b * MAT_STRIDE;
  const long cstride = (long)T_NBATCH * MAT_STRIDE;
  float q0 = Tb[i * 4 + i];
  float q1 = Tb[((i ^ 1) * 4) + i];
  float q2 = Tb[((i ^ 2) * 4) + i];
  float q3 = Tb[((i ^ 3) * 4) + i];
  float q4 = Tb[16 + i];
  for (int c = 0; c < nchunks; ++c) {
    const float* Tn = Tb + cstride;
    float n0 = 0, n1 = 0, n2 = 0, n3 = 0, n4 = 0;
    if (c + 1 < nchunks) {
      n0 = Tn[i * 4 + i];
      n1 = Tn[((i ^ 1) * 4) + i];
      n2 = Tn[((i ^ 2) * 4) + i];
      n3 = Tn[((i ^ 3) * 4) + i];
      n4 = Tn[16 + i];
    }
    const float vx1 = __shfl_xor(v, 1);
    const float vx2 = __shfl_xor(v, 2);
    const float vx3 = __shfl_xor(v, 3);
    const float a0 = q0 + v;
    const float a1 = q1 + vx1;
    const float a2 = q2 + vx2;
    const float a3 = q3 + vx3;
    const float a4 = q4;
    float m = fmaxf(fmaxf(a0, a1), fmaxf(fmaxf(a2, a3), a4));
    v = m + __logf(__expf(a0 - m) + __expf(a1 - m) + __expf(a2 - m) +
                   __expf(a3 - m) + __expf(a4 - m));
    q0 = n0; q1 = n1; q2 = n2; q3 = n3; q4 = n4;
    Tb = Tn;
  }
  float m1 = fmaxf(v, __shfl_xor(v, 1));
  m1 = fmaxf(m1, __shfl_xor(m1, 2));
  float e = __expf(v - m1);
  e += __shfl_xor(e, 1);
  e += __shfl_xor(e, 2);
  const float lz = m1 + __logf(e);
  if (i == 0) logz[b] = lz * (1.0f / (float)T_NTIME);
}

// ---------- K3: out[t][b][8..15] -= logZ[b]/T ----------
__global__ void k_sub(float* __restrict__ out, const float* __restrict__ logz) {
  const long n = (long)blockIdx.x * blockDim.x + threadIdx.x;
  if (n >= (long)T_NROWS * 2) return;
  const long tb = n >> 1;
  const int b = (int)(tb & (T_NBATCH - 1));
  const float lz = logz[b];
  float4* p = (float4*)(out + tb * T_SIZE + 8 + (n & 1) * 4);
  float4 v = *p;
  v.x -= lz; v.y -= lz; v.z -= lz; v.w -= lz;
  *p = v;
}

extern "C" void kernel_launch(void* const* d_in, const int* in_sizes, int n_in,
                              void* d_out, int out_size, void* d_ws, size_t ws_size,
                              hipStream_t stream) {
  const float* x    = (const float*)d_in[0];
  const float* W    = (const float*)d_in[1];
  const float* bias = (const float*)d_in[2];
  float* out = (float*)d_out;
  float* ws  = (float*)d_ws;

  int C = 64;
  while (C > 1 && (size_t)((long)C * T_NBATCH * MAT_STRIDE + T_NBATCH) * 4 > ws_size) C >>= 1;
  float* mats = ws;
  float* logz = ws + (long)C * T_NBATCH * MAT_STRIDE;

  k_gemm_act<<<T_NROWS / 256, 256, 0, stream>>>(x, W, bias, out);

  const int thr2 = C * T_NBATCH * 8;
  k_scan_chunks<<<thr2 / 256, 256, 0, stream>>>(out, mats, C);
  k_combine<<<1, 512, 0, stream>>>(mats, logz, C);
  k_sub<<<(T_NROWS * 2) / 256, 256, 0, stream>>>(out, logz);
}

// Round 7
// 258.991 us; speedup vs baseline: 1.1737x; 1.1737x over previous
//
#include <hip/hip_runtime.h>
#include <math.h>

#define T_NTIME  2048
#define T_NBATCH 128
#define T_INSIZE 512
#define T_SIZE   16
#define T_NROWS  (T_NTIME * T_NBATCH)
#define MAT_STRIDE 24   // padded per-(chunk,b) transfer-matrix stride (floats)

__device__ __forceinline__ float sp_f(float v) {
  return fmaxf(v, 0.0f) + log1pf(__expf(-fabsf(v)));
}
__device__ __forceinline__ float tanh5_f(float v) {
  float a = fabsf(v);
  float e = __expf(-2.0f * a);
  float t = (1.0f - e) / (1.0f + e);
  return copysignf(5.0f * t, v);
}
__device__ __forceinline__ float lae_f(float a, float c) {
  float m = fmaxf(a, c);
  return m + log1pf(__expf(-fabsf(a - c)));
}

__device__ __forceinline__ void emit_row(float* op, const float (&acc)[T_SIZE],
                                         const float* __restrict__ bias) {
  float4 v;
  v.x = 1.0f + sp_f(acc[0] + bias[0]);
  v.y = 1.0f + sp_f(acc[1] + bias[1]);
  v.z = 1.0f + sp_f(acc[2] + bias[2]);
  v.w = 1.0f + sp_f(acc[3] + bias[3]);
  *(float4*)(op + 0) = v;
  v.x = 0.1f + sp_f(acc[4] + bias[4]);
  v.y = 0.1f + sp_f(acc[5] + bias[5]);
  v.z = 0.1f + sp_f(acc[6] + bias[6]);
  v.w = 0.1f + sp_f(acc[7] + bias[7]);
  *(float4*)(op + 4) = v;
  v.x = tanh5_f(acc[8] + bias[8]);
  v.y = tanh5_f(acc[9] + bias[9]);
  v.z = tanh5_f(acc[10] + bias[10]);
  v.w = tanh5_f(acc[11] + bias[11]);
  *(float4*)(op + 8) = v;
  v.x = tanh5_f(acc[12] + bias[12]);
  v.y = tanh5_f(acc[13] + bias[13]);
  v.z = tanh5_f(acc[14] + bias[14]);
  v.w = tanh5_f(acc[15] + bias[15]);
  *(float4*)(op + 12) = v;
}

// ---------- K1: y = x @ W^T + b, activations; trans written pre-logZ ----------
// R5 structure (2 rows/thread, W broadcast from LDS) + per-wave rotation of the
// 128B line-slot walk order. Row-per-lane loads put all 64 lanes' lines at the
// SAME column bits (2KB stride aliasing -> narrow L2/HBM channel slice). Waves
// start at rotated slots so concurrent lines cover all 16 slots -> channels
// load-balance. rot is wave-uniform: W LDS reads stay broadcast.
__global__ __launch_bounds__(256, 2)
void k_gemm_act(const float* __restrict__ x, const float* __restrict__ W,
                const float* __restrict__ bias, float* __restrict__ out) {
  __shared__ float wl[T_SIZE * T_INSIZE];  // 32 KB
  const int tid = threadIdx.x;
  {
    const float4* src = (const float4*)W;
    float4* dst = (float4*)wl;
#pragma unroll
    for (int k = 0; k < 8; ++k) dst[tid + k * 256] = src[tid + k * 256];
  }
  __syncthreads();

  const long row0 = (long)blockIdx.x * 512 + tid;   // and row0 + 256
  const float* __restrict__ xp0 = x + row0 * T_INSIZE;
  const float* __restrict__ xp1 = xp0 + 256L * T_INSIZE;

  const int rot = ((tid >> 6) + ((blockIdx.x & 3) << 2)) & 15;

  float acc0[T_SIZE], acc1[T_SIZE];
#pragma unroll
  for (int s = 0; s < T_SIZE; ++s) { acc0[s] = 0.0f; acc1[s] = 0.0f; }

  // 64 steps of 8 floats (2xfloat4) per row; line-slot p = step>>2 rotated.
#define EFF_OFF(step) (((((((step) >> 2) + rot) & 15) << 2) | ((step) & 3)) * 8)

  float4 cA0, cA1, cB0, cB1, nA0, nA1, nB0, nB1;
  {
    const int off = EFF_OFF(0);
    cA0 = *(const float4*)(xp0 + off);
    cA1 = *(const float4*)(xp0 + off + 4);
    cB0 = *(const float4*)(xp1 + off);
    cB1 = *(const float4*)(xp1 + off + 4);
  }

#pragma unroll 1
  for (int step = 0; step < 64; ++step) {
    if (step < 63) {
      const int offn = EFF_OFF(step + 1);
      nA0 = *(const float4*)(xp0 + offn);
      nA1 = *(const float4*)(xp0 + offn + 4);
      nB0 = *(const float4*)(xp1 + offn);
      nB1 = *(const float4*)(xp1 + offn + 4);
    }
    const int off = EFF_OFF(step);
    const float* wbase = wl + off;   // wave-uniform -> broadcast ds_read_b128
#pragma unroll
    for (int s = 0; s < T_SIZE; ++s) {
      const float4 w4a = *(const float4*)(wbase + s * T_INSIZE);
      acc0[s] = fmaf(cA0.x, w4a.x, acc0[s]);
      acc0[s] = fmaf(cA0.y, w4a.y, acc0[s]);
      acc0[s] = fmaf(cA0.z, w4a.z, acc0[s]);
      acc0[s] = fmaf(cA0.w, w4a.w, acc0[s]);
      acc1[s] = fmaf(cB0.x, w4a.x, acc1[s]);
      acc1[s] = fmaf(cB0.y, w4a.y, acc1[s]);
      acc1[s] = fmaf(cB0.z, w4a.z, acc1[s]);
      acc1[s] = fmaf(cB0.w, w4a.w, acc1[s]);
      const float4 w4b = *(const float4*)(wbase + s * T_INSIZE + 4);
      acc0[s] = fmaf(cA1.x, w4b.x, acc0[s]);
      acc0[s] = fmaf(cA1.y, w4b.y, acc0[s]);
      acc0[s] = fmaf(cA1.z, w4b.z, acc0[s]);
      acc0[s] = fmaf(cA1.w, w4b.w, acc0[s]);
      acc1[s] = fmaf(cB1.x, w4b.x, acc1[s]);
      acc1[s] = fmaf(cB1.y, w4b.y, acc1[s]);
      acc1[s] = fmaf(cB1.z, w4b.z, acc1[s]);
      acc1[s] = fmaf(cB1.w, w4b.w, acc1[s]);
    }
    cA0 = nA0; cA1 = nA1; cB0 = nB0; cB1 = nB1;
  }
#undef EFF_OFF

  emit_row(out + row0 * T_SIZE, acc0, bias);
  emit_row(out + (row0 + 256L) * T_SIZE, acc1, bias);
}

// ---------- K2a: per-(b, chunk, basis-col) chunk transfer-matrix columns ----------
__global__ void k_scan_chunks(const float* __restrict__ out, float* __restrict__ mats,
                              int nchunks) {
  const int gtid = blockIdx.x * blockDim.x + threadIdx.x;
  const int colslot = gtid & 7;
  const int b = (gtid >> 3) & (T_NBATCH - 1);
  const int chunk = gtid >> 10;
  if (chunk >= nchunks) return;
  if (colslot >= 5) return;

  const int steps = T_NTIME / nchunks;
  const int t0 = chunk * steps;
  const float NEG = -1e30f;
  float f0 = (colslot == 0) ? 0.0f : NEG;
  float f1 = (colslot == 1) ? 0.0f : NEG;
  float f2 = (colslot == 2) ? 0.0f : NEG;
  float f3 = (colslot == 3) ? 0.0f : NEG;
  const float t4 = (colslot == 4) ? 0.0f : NEG;

  const long stride = T_NBATCH * T_SIZE;
  const float* p = out + ((long)t0 * T_NBATCH + b) * T_SIZE + 8;
  float4 mv = *(const float4*)(p);
  float4 st = *(const float4*)(p + 4);
  for (int s = 0; s < steps; ++s) {
    const float* pn = (s + 1 < steps) ? p + stride : p;
    const float4 mvn = *(const float4*)(pn);
    const float4 stn = *(const float4*)(pn + 4);

    float m, ss0, ss1, ss2, ss3;
    m = fmaxf(fmaxf(f1, f2), fmaxf(f3, t4));
    ss0 = m + __logf(__expf(f1 - m) + __expf(f2 - m) + __expf(f3 - m) + __expf(t4 - m));
    m = fmaxf(fmaxf(f0, f2), fmaxf(f3, t4));
    ss1 = m + __logf(__expf(f0 - m) + __expf(f2 - m) + __expf(f3 - m) + __expf(t4 - m));
    m = fmaxf(fmaxf(f0, f1), fmaxf(f3, t4));
    ss2 = m + __logf(__expf(f0 - m) + __expf(f1 - m) + __expf(f3 - m) + __expf(t4 - m));
    m = fmaxf(fmaxf(f0, f1), fmaxf(f2, t4));
    ss3 = m + __logf(__expf(f0 - m) + __expf(f1 - m) + __expf(f2 - m) + __expf(t4 - m));

    const float n0 = lae_f(f0 + st.x, ss0 + mv.x);
    const float n1 = lae_f(f1 + st.y, ss1 + mv.y);
    const float n2 = lae_f(f2 + st.z, ss2 + mv.z);
    const float n3 = lae_f(f3 + st.w, ss3 + mv.w);
    f0 = n0; f1 = n1; f2 = n2; f3 = n3;
    mv = mvn; st = stn; p = pn;
  }
  float* d = mats + ((long)chunk * T_NBATCH + b) * MAT_STRIDE + colslot * 4;
  float4 o; o.x = f0; o.y = f1; o.z = f2; o.w = f3;
  *(float4*)d = o;
}

// ---------- K2b: serial combine of chunk matrices per batch; logZ/T out ----------
__global__ void k_combine(const float* __restrict__ mats, float* __restrict__ logz,
                          int nchunks) {
  const int tid = threadIdx.x;       // 0..511
  const int i = tid & 3;             // state row
  const int b = tid >> 2;            // batch
  if (b >= T_NBATCH) return;
  float v = 0.0f;                    // v[i]; implicit v[4] = 0 constant

  const float* Tb = mats + (long)b * MAT_STRIDE;
  const long cstride = (long)T_NBATCH * MAT_STRIDE;
  float q0 = Tb[i * 4 + i];
  float q1 = Tb[((i ^ 1) * 4) + i];
  float q2 = Tb[((i ^ 2) * 4) + i];
  float q3 = Tb[((i ^ 3) * 4) + i];
  float q4 = Tb[16 + i];
  for (int c = 0; c < nchunks; ++c) {
    const float* Tn = Tb + cstride;
    float n0 = 0, n1 = 0, n2 = 0, n3 = 0, n4 = 0;
    if (c + 1 < nchunks) {
      n0 = Tn[i * 4 + i];
      n1 = Tn[((i ^ 1) * 4) + i];
      n2 = Tn[((i ^ 2) * 4) + i];
      n3 = Tn[((i ^ 3) * 4) + i];
      n4 = Tn[16 + i];
    }
    const float vx1 = __shfl_xor(v, 1);
    const float vx2 = __shfl_xor(v, 2);
    const float vx3 = __shfl_xor(v, 3);
    const float a0 = q0 + v;
    const float a1 = q1 + vx1;
    const float a2 = q2 + vx2;
    const float a3 = q3 + vx3;
    const float a4 = q4;
    float m = fmaxf(fmaxf(a0, a1), fmaxf(fmaxf(a2, a3), a4));
    v = m + __logf(__expf(a0 - m) + __expf(a1 - m) + __expf(a2 - m) +
                   __expf(a3 - m) + __expf(a4 - m));
    q0 = n0; q1 = n1; q2 = n2; q3 = n3; q4 = n4;
    Tb = Tn;
  }
  float m1 = fmaxf(v, __shfl_xor(v, 1));
  m1 = fmaxf(m1, __shfl_xor(m1, 2));
  float e = __expf(v - m1);
  e += __shfl_xor(e, 1);
  e += __shfl_xor(e, 2);
  const float lz = m1 + __logf(e);
  if (i == 0) logz[b] = lz * (1.0f / (float)T_NTIME);
}

// ---------- K3: out[t][b][8..15] -= logZ[b]/T ----------
__global__ void k_sub(float* __restrict__ out, const float* __restrict__ logz) {
  const long n = (long)blockIdx.x * blockDim.x + threadIdx.x;
  if (n >= (long)T_NROWS * 2) return;
  const long tb = n >> 1;
  const int b = (int)(tb & (T_NBATCH - 1));
  const float lz = logz[b];
  float4* p = (float4*)(out + tb * T_SIZE + 8 + (n & 1) * 4);
  float4 v = *p;
  v.x -= lz; v.y -= lz; v.z -= lz; v.w -= lz;
  *p = v;
}

extern "C" void kernel_launch(void* const* d_in, const int* in_sizes, int n_in,
                              void* d_out, int out_size, void* d_ws, size_t ws_size,
                              hipStream_t stream) {
  const float* x    = (const float*)d_in[0];
  const float* W    = (const float*)d_in[1];
  const float* bias = (const float*)d_in[2];
  float* out = (float*)d_out;
  float* ws  = (float*)d_ws;

  int C = 64;
  while (C > 1 && (size_t)((long)C * T_NBATCH * MAT_STRIDE + T_NBATCH) * 4 > ws_size) C >>= 1;
  float* mats = ws;
  float* logz = ws + (long)C * T_NBATCH * MAT_STRIDE;

  k_gemm_act<<<T_NROWS / 512, 256, 0, stream>>>(x, W, bias, out);

  const int thr2 = C * T_NBATCH * 8;
  k_scan_chunks<<<thr2 / 256, 256, 0, stream>>>(out, mats, C);
  k_combine<<<1, 512, 0, stream>>>(mats, logz, C);
  k_sub<<<(T_NROWS * 2) / 256, 256, 0, stream>>>(out, logz);
}

// Round 8
// 198.984 us; speedup vs baseline: 1.5276x; 1.3016x over previous
//
#include <hip/hip_runtime.h>
#include <math.h>

#define T_NTIME  2048
#define T_NBATCH 128
#define T_INSIZE 512
#define T_SIZE   16
#define T_NROWS  (T_NTIME * T_NBATCH)
#define MAT_STRIDE 24

typedef __attribute__((ext_vector_type(8))) short s8v;    // 8 bf16 (4 VGPR)
typedef __attribute__((ext_vector_type(4))) float f32x4;  // MFMA acc

__device__ __forceinline__ float sp_f(float v) {
  return fmaxf(v, 0.0f) + log1pf(__expf(-fabsf(v)));
}
__device__ __forceinline__ float tanh5_f(float v) {
  float a = fabsf(v);
  float e = __expf(-2.0f * a);
  float t = (1.0f - e) / (1.0f + e);
  return copysignf(5.0f * t, v);
}
__device__ __forceinline__ float lae_f(float a, float c) {
  float m = fmaxf(a, c);
  return m + log1pf(__expf(-fabsf(a - c)));
}
// round-to-nearest-even f32 -> bf16 bits, and the exact residual
__device__ __forceinline__ void bf16_split(float f, short& hi, short& lo) {
  unsigned u = __float_as_uint(f);
  unsigned hb = (u + 0x7fffu + ((u >> 16) & 1u)) >> 16;
  float hf = __uint_as_float(hb << 16);
  float l = f - hf;
  unsigned ul = __float_as_uint(l);
  unsigned lb = (ul + 0x7fffu + ((ul >> 16) & 1u)) >> 16;
  hi = (short)hb;
  lo = (short)lb;
}

// ---------- K1: MFMA GEMM  out = act(x @ W^T + b), trans pre-logZ ----------
// M=16(s) x K=512 x N=262144(rows). Tile: 16 rows staged in LDS (dbuf),
// coalesced reg-staging (lane reads consecutive float4 -> linear HBM stream),
// XOR-swizzled LDS slots. bf16 hi/lo split => f32-grade accuracy.
// Wave w owns k-chunks [4w,4w+4); W A-frags resident in VGPRs; cross-wave
// reduce in LDS (parity dbuf); wave0 activates + stores.
__global__ __launch_bounds__(256, 2)
void k1_mfma(const float* __restrict__ x, const float* __restrict__ W,
             const float* __restrict__ bias, float* __restrict__ out) {
  __shared__ float4 xb[2][2048];     // 2 x 16 rows x 128 chunks (64 KB)
  __shared__ float4 red[2][3][64];   // 6 KB
  const int tid = threadIdx.x;
  const int l = tid & 63;
  const int w = tid >> 6;
  const int lr = l & 15;   // x-row within tile (B n-index) / W s-row (A m-index)
  const int lk = l >> 4;   // k-subgroup 0..3
  const int r7 = lr & 7;

  // one-time: A-frags of W (hi/lo) for this wave's 4 k-chunks
  s8v ah[4], al[4];
#pragma unroll
  for (int kc2 = 0; kc2 < 4; ++kc2) {
    const float* wp = W + lr * T_INSIZE + (w * 4 + kc2) * 32 + lk * 8;
    const float4 a0 = *(const float4*)(wp);
    const float4 a1 = *(const float4*)(wp + 4);
    const float f[8] = {a0.x, a0.y, a0.z, a0.w, a1.x, a1.y, a1.z, a1.w};
#pragma unroll
    for (int j = 0; j < 8; ++j) {
      short h, lo2; bf16_split(f[j], h, lo2);
      ah[kc2][j] = h; al[kc2][j] = lo2;
    }
  }
  const float4 bv = *(const float4*)(bias + lk * 4);

  const long rowbase = (long)blockIdx.x * 512;
  const float* xbase = x + rowbase * T_INSIZE;

  // prologue: stage tile 0 (coalesced load -> swizzled LDS write)
#pragma unroll
  for (int j = 0; j < 8; ++j) {
    const int q = w * 8 + j;
    const float4 v = *(const float4*)(xbase + q * 256 + l * 4);
    const int r = q >> 1;
    const int c = ((q & 1) << 6) | l;
    xb[0][r * 128 + (c ^ (r & 7))] = v;
  }
  __syncthreads();

  for (int t = 0; t < 32; ++t) {
    // issue next tile's global loads early (fly under compute)
    float4 stg0, stg1, stg2, stg3, stg4, stg5, stg6, stg7;
    if (t + 1 < 32) {
      const float* src = xbase + (long)(t + 1) * 16 * T_INSIZE;
      const int q0 = w * 8;
      stg0 = *(const float4*)(src + (q0 + 0) * 256 + l * 4);
      stg1 = *(const float4*)(src + (q0 + 1) * 256 + l * 4);
      stg2 = *(const float4*)(src + (q0 + 2) * 256 + l * 4);
      stg3 = *(const float4*)(src + (q0 + 3) * 256 + l * 4);
      stg4 = *(const float4*)(src + (q0 + 4) * 256 + l * 4);
      stg5 = *(const float4*)(src + (q0 + 5) * 256 + l * 4);
      stg6 = *(const float4*)(src + (q0 + 6) * 256 + l * 4);
      stg7 = *(const float4*)(src + (q0 + 7) * 256 + l * 4);
    }

    // compute tile t
    const float4* bufp = xb[t & 1];
    f32x4 acc = {0.f, 0.f, 0.f, 0.f};
#pragma unroll
    for (int kc2 = 0; kc2 < 4; ++kc2) {
      const int cbase = (w * 4 + kc2) * 8 + lk * 2;
      const float4 b0 = bufp[lr * 128 + (cbase ^ r7)];
      const float4 b1 = bufp[lr * 128 + ((cbase + 1) ^ r7)];
      s8v bh, bl2;
      const float f[8] = {b0.x, b0.y, b0.z, b0.w, b1.x, b1.y, b1.z, b1.w};
#pragma unroll
      for (int j = 0; j < 8; ++j) {
        short h, lo2; bf16_split(f[j], h, lo2);
        bh[j] = h; bl2[j] = lo2;
      }
      acc = __builtin_amdgcn_mfma_f32_16x16x32_bf16(ah[kc2], bh, acc, 0, 0, 0);
      acc = __builtin_amdgcn_mfma_f32_16x16x32_bf16(ah[kc2], bl2, acc, 0, 0, 0);
      acc = __builtin_amdgcn_mfma_f32_16x16x32_bf16(al[kc2], bh, acc, 0, 0, 0);
    }

    // late LDS write of the staged tile into the other buffer
    if (t + 1 < 32) {
      float4* dst = xb[(t + 1) & 1];
      const int q0 = w * 8;
#define STW(J, V)                                                   \
      { const int q = q0 + (J); const int r = q >> 1;               \
        const int c = ((q & 1) << 6) | l;                           \
        dst[r * 128 + (c ^ (r & 7))] = (V); }
      STW(0, stg0) STW(1, stg1) STW(2, stg2) STW(3, stg3)
      STW(4, stg4) STW(5, stg5) STW(6, stg6) STW(7, stg7)
#undef STW
    }

    // cross-wave partials
    if (w != 0) {
      float4 p; p.x = acc[0]; p.y = acc[1]; p.z = acc[2]; p.w = acc[3];
      red[t & 1][w - 1][l] = p;
    }
    __syncthreads();

    if (w == 0) {
      const float4 p1 = red[t & 1][0][l];
      const float4 p2 = red[t & 1][1][l];
      const float4 p3 = red[t & 1][2][l];
      const float y0 = acc[0] + p1.x + p2.x + p3.x + bv.x;
      const float y1 = acc[1] + p1.y + p2.y + p3.y + bv.y;
      const float y2 = acc[2] + p1.z + p2.z + p3.z + bv.z;
      const float y3 = acc[3] + p1.w + p2.w + p3.w + bv.w;
      float4 o;
      if (lk == 0) {
        o.x = 1.0f + sp_f(y0); o.y = 1.0f + sp_f(y1);
        o.z = 1.0f + sp_f(y2); o.w = 1.0f + sp_f(y3);
      } else if (lk == 1) {
        o.x = 0.1f + sp_f(y0); o.y = 0.1f + sp_f(y1);
        o.z = 0.1f + sp_f(y2); o.w = 0.1f + sp_f(y3);
      } else {
        o.x = tanh5_f(y0); o.y = tanh5_f(y1);
        o.z = tanh5_f(y2); o.w = tanh5_f(y3);
      }
      *(float4*)(out + (rowbase + (long)t * 16 + lr) * T_SIZE + lk * 4) = o;
    }
  }
}

// ---------- K2a: per-(b, chunk, basis-col) chunk transfer-matrix columns ----------
__global__ void k_scan_chunks(const float* __restrict__ out, float* __restrict__ mats,
                              int nchunks) {
  const int gtid = blockIdx.x * blockDim.x + threadIdx.x;
  const int colslot = gtid & 7;
  const int b = (gtid >> 3) & (T_NBATCH - 1);
  const int chunk = gtid >> 10;
  if (chunk >= nchunks) return;
  if (colslot >= 5) return;

  const int steps = T_NTIME / nchunks;
  const int t0 = chunk * steps;
  const float NEG = -1e30f;
  float f0 = (colslot == 0) ? 0.0f : NEG;
  float f1 = (colslot == 1) ? 0.0f : NEG;
  float f2 = (colslot == 2) ? 0.0f : NEG;
  float f3 = (colslot == 3) ? 0.0f : NEG;
  const float t4 = (colslot == 4) ? 0.0f : NEG;

  const long stride = T_NBATCH * T_SIZE;
  const float* p = out + ((long)t0 * T_NBATCH + b) * T_SIZE + 8;
  float4 mv = *(const float4*)(p);
  float4 st = *(const float4*)(p + 4);
  for (int s = 0; s < steps; ++s) {
    const float* pn = (s + 1 < steps) ? p + stride : p;
    const float4 mvn = *(const float4*)(pn);
    const float4 stn = *(const float4*)(pn + 4);

    float m, ss0, ss1, ss2, ss3;
    m = fmaxf(fmaxf(f1, f2), fmaxf(f3, t4));
    ss0 = m + __logf(__expf(f1 - m) + __expf(f2 - m) + __expf(f3 - m) + __expf(t4 - m));
    m = fmaxf(fmaxf(f0, f2), fmaxf(f3, t4));
    ss1 = m + __logf(__expf(f0 - m) + __expf(f2 - m) + __expf(f3 - m) + __expf(t4 - m));
    m = fmaxf(fmaxf(f0, f1), fmaxf(f3, t4));
    ss2 = m + __logf(__expf(f0 - m) + __expf(f1 - m) + __expf(f3 - m) + __expf(t4 - m));
    m = fmaxf(fmaxf(f0, f1), fmaxf(f2, t4));
    ss3 = m + __logf(__expf(f0 - m) + __expf(f1 - m) + __expf(f2 - m) + __expf(t4 - m));

    const float n0 = lae_f(f0 + st.x, ss0 + mv.x);
    const float n1 = lae_f(f1 + st.y, ss1 + mv.y);
    const float n2 = lae_f(f2 + st.z, ss2 + mv.z);
    const float n3 = lae_f(f3 + st.w, ss3 + mv.w);
    f0 = n0; f1 = n1; f2 = n2; f3 = n3;
    mv = mvn; st = stn; p = pn;
  }
  float* d = mats + ((long)chunk * T_NBATCH + b) * MAT_STRIDE + colslot * 4;
  float4 o; o.x = f0; o.y = f1; o.z = f2; o.w = f3;
  *(float4*)d = o;
}

// ---------- K2b: serial combine of chunk matrices per batch; logZ/T out ----------
__global__ void k_combine(const float* __restrict__ mats, float* __restrict__ logz,
                          int nchunks) {
  const int tid = threadIdx.x;
  const int i = tid & 3;
  const int b = tid >> 2;
  if (b >= T_NBATCH) return;
  float v = 0.0f;

  const float* Tb = mats + (long)b * MAT_STRIDE;
  const long cstride = (long)T_NBATCH * MAT_STRIDE;
  float q0 = Tb[i * 4 + i];
  float q1 = Tb[((i ^ 1) * 4) + i];
  float q2 = Tb[((i ^ 2) * 4) + i];
  float q3 = Tb[((i ^ 3) * 4) + i];
  float q4 = Tb[16 + i];
  for (int c = 0; c < nchunks; ++c) {
    const float* Tn = Tb + cstride;
    float n0 = 0, n1 = 0, n2 = 0, n3 = 0, n4 = 0;
    if (c + 1 < nchunks) {
      n0 = Tn[i * 4 + i];
      n1 = Tn[((i ^ 1) * 4) + i];
      n2 = Tn[((i ^ 2) * 4) + i];
      n3 = Tn[((i ^ 3) * 4) + i];
      n4 = Tn[16 + i];
    }
    const float vx1 = __shfl_xor(v, 1);
    const float vx2 = __shfl_xor(v, 2);
    const float vx3 = __shfl_xor(v, 3);
    const float a0 = q0 + v;
    const float a1 = q1 + vx1;
    const float a2 = q2 + vx2;
    const float a3 = q3 + vx3;
    const float a4 = q4;
    float m = fmaxf(fmaxf(a0, a1), fmaxf(fmaxf(a2, a3), a4));
    v = m + __logf(__expf(a0 - m) + __expf(a1 - m) + __expf(a2 - m) +
                   __expf(a3 - m) + __expf(a4 - m));
    q0 = n0; q1 = n1; q2 = n2; q3 = n3; q4 = n4;
    Tb = Tn;
  }
  float m1 = fmaxf(v, __shfl_xor(v, 1));
  m1 = fmaxf(m1, __shfl_xor(m1, 2));
  float e = __expf(v - m1);
  e += __shfl_xor(e, 1);
  e += __shfl_xor(e, 2);
  const float lz = m1 + __logf(e);
  if (i == 0) logz[b] = lz * (1.0f / (float)T_NTIME);
}

// ---------- K3: out[t][b][8..15] -= logZ[b]/T ----------
__global__ void k_sub(float* __restrict__ out, const float* __restrict__ logz) {
  const long n = (long)blockIdx.x * blockDim.x + threadIdx.x;
  if (n >= (long)T_NROWS * 2) return;
  const long tb = n >> 1;
  const int b = (int)(tb & (T_NBATCH - 1));
  const float lz = logz[b];
  float4* p = (float4*)(out + tb * T_SIZE + 8 + (n & 1) * 4);
  float4 v = *p;
  v.x -= lz; v.y -= lz; v.z -= lz; v.w -= lz;
  *p = v;
}

extern "C" void kernel_launch(void* const* d_in, const int* in_sizes, int n_in,
                              void* d_out, int out_size, void* d_ws, size_t ws_size,
                              hipStream_t stream) {
  const float* x    = (const float*)d_in[0];
  const float* W    = (const float*)d_in[1];
  const float* bias = (const float*)d_in[2];
  float* out = (float*)d_out;
  float* ws  = (float*)d_ws;

  int C = 64;
  while (C > 1 && (size_t)((long)C * T_NBATCH * MAT_STRIDE + T_NBATCH) * 4 > ws_size) C >>= 1;
  float* mats = ws;
  float* logz = ws + (long)C * T_NBATCH * MAT_STRIDE;

  k1_mfma<<<T_NROWS / 512, 256, 0, stream>>>(x, W, bias, out);

  const int thr2 = C * T_NBATCH * 8;
  k_scan_chunks<<<thr2 / 256, 256, 0, stream>>>(out, mats, C);
  k_combine<<<1, 512, 0, stream>>>(mats, logz, C);
  k_sub<<<(T_NROWS * 2) / 256, 256, 0, stream>>>(out, logz);
}